// Round 1
// baseline (12.850 us; speedup 1.0000x reference)
//
#include <hip/hip_runtime.h>

__device__ __forceinline__ unsigned quantq(float v) {
    // (x * 256).clamp(0, 255) -> int truncation (values nonneg after clamp)
    v = v * 256.0f;
    v = fminf(fmaxf(v, 0.0f), 255.0f);
    return (unsigned)v;
}

__global__ __launch_bounds__(1024) void adder2d_kernel(
    const float* __restrict__ x, const float* __restrict__ W,
    float* __restrict__ out)
{
    const int tid = threadIdx.x;
    const int bid = blockIdx.x;
    const int n = bid >> 5;   // batch
    const int i = bid & 31;   // output row

    // 296 = 288 + 8 pad (keeps 16B row alignment: 592B rows). Pad never read.
    __shared__ __align__(16) unsigned short sQW[32][296];  // [f][k] quantized W
    __shared__ __align__(16) unsigned short sQX[32][296];  // [j][k] im2col row, quantized
    __shared__ unsigned char sRow[3072];                   // [c][kh][w] quantized input rows

    // Phase 1a: quantize W -> sQW[f][k], k = c*9 + kh*3 + kw (same layout as W flat)
    for (int idx = tid; idx < 9216; idx += 1024) {
        int f = idx / 288;
        int k = idx - f * 288;
        sQW[f][k] = (unsigned short)quantq(W[idx]);
    }
    // Phase 1b: load+quantize input rows i-1, i, i+1 (zero pad rows -> q=0)
    for (int idx = tid; idx < 3072; idx += 1024) {
        int c = idx / 96;
        int rem = idx - c * 96;
        int rr = rem >> 5;          // 0..2 (kh)
        int w = rem & 31;
        int r = i + rr - 1;
        float v = (r >= 0 && r < 32) ? x[((n * 32 + c) * 32 + r) * 32 + w] : 0.0f;
        sRow[idx] = (unsigned char)quantq(v);
    }
    __syncthreads();

    // Phase 2: build im2col quantized row sQX[j][k]
    for (int idx = tid; idx < 9216; idx += 1024) {
        int j = idx / 288;
        int k = idx - j * 288;
        int c = k / 9;
        int rem = k - c * 9;
        int kh = rem / 3;
        int kw = rem - kh * 3;
        int col = j + kw - 1;
        unsigned v = (col >= 0 && col < 32) ? (unsigned)sRow[c * 96 + kh * 32 + col] : 0u;
        sQX[j][k] = (unsigned short)v;
    }
    __syncthreads();

    // Phase 3: each thread computes out[n][f][i][j]
    const int f = tid >> 5;
    const int j = tid & 31;
    const uint4* qwr = (const uint4*)(&sQW[f][0]);
    const uint4* qxr = (const uint4*)(&sQX[j][0]);
    unsigned acc = 0;  // two 16-bit lane accumulators; max 144*255 = 36720 < 65536
#pragma unroll 6
    for (int g = 0; g < 36; ++g) {   // 36 uint4 = 144 u32 = 288 u16 terms, exact
        uint4 a = qwr[g];
        uint4 b = qxr[g];
        // per-16-bit-lane: (qw + qx) <= 510, no cross-lane carry; & 0xff == mod 256
        acc += ((a.x + b.x) & 0x00ff00ffu);
        acc += ((a.y + b.y) & 0x00ff00ffu);
        acc += ((a.z + b.z) & 0x00ff00ffu);
        acc += ((a.w + b.w) & 0x00ff00ffu);
    }
    unsigned total = (acc & 0xffffu) + (acc >> 16);
    out[((n * 32 + f) * 32 + i) * 32 + j] = -(float)total * (1.0f / 256.0f);
}

extern "C" void kernel_launch(void* const* d_in, const int* in_sizes, int n_in,
                              void* d_out, int out_size, void* d_ws, size_t ws_size,
                              hipStream_t stream) {
    const float* x = (const float*)d_in[0];   // [8,32,32,32]
    const float* W = (const float*)d_in[1];   // [32,32,3,3]
    float* out = (float*)d_out;               // [8,32,32,32]
    adder2d_kernel<<<256, 1024, 0, stream>>>(x, W, out);
}